// Round 6
// baseline (326.061 us; speedup 1.0000x reference)
//
#include <hip/hip_runtime.h>

#define DDIM   4        // D = 2*K-2
#define CIN    64
#define COUT   128
#define CDIM   256      // CIN*DDIM
#define HH     128
#define WWID   128
#define NN     4
#define KK     9        // K*K
#define OFFC   18       // 2*K*K
#define HW     (HH * WWID)

// ---- LDS layout (floats) ----
// xs: 8 wave-private slices of 511 floats (phase0 uses 3x66=198, phase1 7 rows x 72 cols @ stride 73)
#define XS_SLICE  511
#define XS_TOTAL  (8 * XS_SLICE)            // 4088
#define TL_OFF    XS_TOTAL                  // tl[18][64] = 1152 floats
#define YL_OFF    (TL_OFF + OFFC * 64)      // 5240
#define SMEM_FLOATS (YL_OFF + 8192)         // ylds 64x256 bf16 = 8192 floats-worth -> 53728 B total
// part bf16[8][18][64] (18432 B) aliases the ylds region, separated by barriers.

typedef __attribute__((ext_vector_type(8))) short bf16x8;
typedef __attribute__((ext_vector_type(4))) float f32x4;

#define RFL(x) __builtin_amdgcn_readfirstlane(x)

__device__ __forceinline__ unsigned short f2bf(float f) {
  union { float f; unsigned u; } c; c.f = f;
  unsigned u = c.u;
  return (unsigned short)((u + 0x7FFFu + ((u >> 16) & 1u)) >> 16);  // RNE
}
__device__ __forceinline__ float bf2f(unsigned short u) {
  union { unsigned u; float f; } c; c.u = (unsigned)u << 16;
  return c.f;
}

__global__ void convert_wpw(const float* __restrict__ w_pw, unsigned short* __restrict__ wbf) {
  int i = blockIdx.x * 256 + threadIdx.x;
  if (i < COUT * CDIM) wbf[i] = f2bf(w_pw[i]);
}

// ---------------------------------------------------------------------------
// Mega-fused kernel: offset-conv + bilinear deform + depthwise + MFMA pointwise.
// 512 thr = 8 waves; strip = 64 pixels (one h row). T14 register prefetch of
// next channel's halo in phases 0 and 1; chunked XCD swizzle for L2 locality.
// ---------------------------------------------------------------------------
__global__ __launch_bounds__(512, 4)
void fused_all(const float* __restrict__ x, const float* __restrict__ w_off,
               const float* __restrict__ b_off, const float* __restrict__ w_deform,
               const unsigned short* __restrict__ wbf, float* __restrict__ out) {
  __shared__ float smem[SMEM_FLOATS];

  // chunked XCD swizzle (bijective: 1024 blocks = 8 XCDs x 128)
  const int lin = blockIdx.x + 2 * blockIdx.y + 256 * blockIdx.z;
  const int swz = ((lin & 7) << 7) + (lin >> 3);
  const int n  = swz >> 8;
  const int h  = (swz >> 1) & 127;
  const int w0 = (swz & 1) * 64;

  const int tid = threadIdx.x;
  const int pl = tid & 63;          // pixel within strip (== lane)
  const int cg = tid >> 6;          // wave id
  const int w = w0 + pl;

  const float* xn = x + (size_t)n * CIN * HW;
  float* xsl = smem + cg * XS_SLICE;                       // wave-private slice
  float* tl  = smem + TL_OFF;                              // [18][64]
  unsigned short* pt   = (unsigned short*)(smem + YL_OFF); // partials (bf16) alias
  unsigned short* ylds = (unsigned short*)(smem + YL_OFF); // [64][256] bf16

  // ==== phase 0: offset-conv partials (this wave's 8 channels), prefetched ====
  float ao[OFFC];
#pragma unroll
  for (int o = 0; o < OFFC; ++o) ao[o] = 0.f;

  // hoisted staging geometry (3 rows x 66 cols, zero-filled borders)
  int g0[4]; unsigned okm = 0;
#pragma unroll
  for (int k = 0; k < 4; ++k) {
    const int i = pl + k * 64;
    const int tr = i / 66, tc = i - tr * 66;
    const int gy = h - 1 + tr, gx = w0 - 1 + tc;
    const bool ok = (i < 198) && gy >= 0 && gy < HH && gx >= 0 && gx < WWID;
    g0[k] = ok ? (gy * WWID + gx) : 0;
    okm |= ok ? (1u << k) : 0u;
  }
  auto p0_load = [&](float* b, int c) {
    const float* xc = xn + (size_t)c * HW;
#pragma unroll
    for (int k = 0; k < 4; ++k) b[k] = ((okm >> k) & 1) ? xc[g0[k]] : 0.f;
  };
  auto p0_write = [&](const float* b) {
#pragma unroll
    for (int k = 0; k < 4; ++k) {
      if (k < 3) xsl[pl + k * 64] = b[k];
      else if (pl < 6) xsl[pl + 192] = b[3];
    }
  };
  auto p0_comp = [&](int c) {
    const float center = xsl[66 + pl + 1];
    float v[KK];
#pragma unroll
    for (int p = 0; p < KK; ++p)
      v[p] = xsl[(p / 3) * 66 + pl + (p % 3)] - center;   // v[4]==0
#pragma unroll
    for (int o = 0; o < OFFC; ++o) {
      const float* wrow = w_off + ((size_t)o * CIN + c) * KK;  // SGPR base
      float a = ao[o];
#pragma unroll
      for (int p = 0; p < KK; ++p) {
        if (p == 4) continue;
        a += wrow[p] * v[p];
      }
      ao[o] = a;
    }
  };

  {
    float pA[4], pB[4];
    p0_load(pA, RFL(cg * 8));
#pragma unroll
    for (int c2 = 0; c2 < 8; c2 += 2) {
      p0_write(pA);
      p0_load(pB, RFL(cg * 8 + c2 + 1));
      p0_comp(RFL(cg * 8 + c2));
      p0_write(pB);
      if (c2 < 6) p0_load(pA, RFL(cg * 8 + c2 + 2));
      p0_comp(RFL(cg * 8 + c2 + 1));
    }
  }
#pragma unroll
  for (int o = 0; o < OFFC; ++o) pt[(cg * OFFC + o) * 64 + pl] = f2bf(ao[o]);
  __syncthreads();

  // ==== cross-wave reduce -> tl[18][64] ====
  for (int idx = tid; idx < OFFC * 64; idx += 512) {
    const int o = idx >> 6, px = idx & 63;
    float s = b_off[o];
#pragma unroll
    for (int w8 = 0; w8 < 8; ++w8) s += bf2f(pt[(w8 * OFFC + o) * 64 + px]);
    tl[o * 64 + px] = s;
  }
  __syncthreads();    // fences pt reads before ylds (alias) writes

  // ==== tap precompute (per pixel pl); 7-row x 72-col window ====
  const int row0 = min(max(h - 3, 0), HH - 7);
  const int col0 = min(max(w0 - 3, 0), WWID - 72);
  const int hc  = h - row0;
  const int wcb = w0 - col0;
  unsigned pk[KK];
  float c00[KK], c01[KK], c10[KK], c11[KK];
  unsigned inmask = 0;
#pragma unroll
  for (int p = 0; p < KK; ++p) {
    const float dy = tl[(2 * p) * 64 + pl];
    const float dx = tl[(2 * p + 1) * 64 + pl];
    const float py  = dy + (float)(h + p / 3 - 1);
    const float pxx = dx + (float)(w + p % 3 - 1);
    const float fy = floorf(py), fx = floorf(pxx);
    const int y0 = (int)fy, x0 = (int)fx;
    const int y1 = y0 + 1,  x1 = x0 + 1;
    const float ay = py - fy, ax = pxx - fx;
    const bool vy0 = (y0 >= 0) && (y0 < HH), vy1 = (y1 >= 0) && (y1 < HH);
    const bool vx0 = (x0 >= 0) && (x0 < WWID), vx1 = (x1 >= 0) && (x1 < WWID);
    const int yc0 = min(max(y0, 0), HH - 1),  yc1 = min(max(y1, 0), HH - 1);
    const int xc0 = min(max(x0, 0), WWID - 1), xc1 = min(max(x1, 0), WWID - 1);
    const int ty0 = yc0 - row0, ty1 = yc1 - row0;
    const int tx0 = xc0 - col0, tx1 = xc1 - col0;
    if ((unsigned)ty0 < 7u && (unsigned)ty1 < 7u && (unsigned)tx0 < 72u && (unsigned)tx1 < 72u)
      inmask |= 1u << p;
    pk[p] = (unsigned)(ty0 & 255) | ((unsigned)(ty1 & 255) << 8)
          | ((unsigned)(tx0 & 255) << 16) | ((unsigned)(tx1 & 255) << 24);
    c00[p] = (vy0 && vx0) ? (1.f - ay) * (1.f - ax) : 0.f;
    c01[p] = (vy0 && vx1) ? (1.f - ay) * ax         : 0.f;
    c10[p] = (vy1 && vx0) ? ay * (1.f - ax)         : 0.f;
    c11[p] = (vy1 && vx1) ? ay * ax                 : 0.f;
  }

  // ==== phase 1: prefetched halo staging + LDS bilinear + depthwise -> ylds ====
  // hoisted geometry: 7x72 window, LDS stride 73
  int g1[8], l1[8];
#pragma unroll
  for (int k = 0; k < 8; ++k) {
    const int i = pl + k * 64;
    const int r = i / 72, cl = i - r * 72;
    g1[k] = (row0 + r) * WWID + col0 + cl;
    l1[k] = r * 73 + cl;
  }
  auto p1_load = [&](float* b, int c) {
    const float* xc = xn + (size_t)c * HW;
#pragma unroll
    for (int k = 0; k < 8; ++k) {
      if (k < 7) b[k] = xc[g1[k]];
      else if (pl < 56) b[7] = xc[g1[7]];
    }
  };
  auto p1_write = [&](const float* b) {
#pragma unroll
    for (int k = 0; k < 8; ++k) {
      if (k < 7) xsl[l1[k]] = b[k];
      else if (pl < 56) xsl[l1[7]] = b[7];
    }
  };
  auto p1_comp = [&](int c) {
    const float* xc = xn + (size_t)c * HW;   // cold path
    const float xcv = xsl[hc * 73 + wcb + pl];
    float yd0 = 0.f, yd1 = 0.f, yd2 = 0.f, yd3 = 0.f;
#pragma unroll
    for (int p = 0; p < KK; ++p) {
      float samp;
      if (inmask & (1u << p)) {             // hot: in-window LDS gather
        const unsigned k4 = pk[p];
        const int ty0 = k4 & 255, ty1 = (k4 >> 8) & 255;
        const int tx0 = (k4 >> 16) & 255, tx1 = k4 >> 24;
        samp = c00[p] * xsl[ty0 * 73 + tx0] + c01[p] * xsl[ty0 * 73 + tx1]
             + c10[p] * xsl[ty1 * 73 + tx0] + c11[p] * xsl[ty1 * 73 + tx1];
      } else {                              // cold: recompute + global gather
        const float dy = tl[(2 * p) * 64 + pl];
        const float dx = tl[(2 * p + 1) * 64 + pl];
        const float py  = dy + (float)(h + p / 3 - 1);
        const float pxx = dx + (float)(w + p % 3 - 1);
        const float fy = floorf(py), fx = floorf(pxx);
        const int y0 = (int)fy, x0 = (int)fx;
        const int yc0 = min(max(y0, 0), HH - 1),  yc1 = min(max(y0 + 1, 0), HH - 1);
        const int xc0 = min(max(x0, 0), WWID - 1), xc1 = min(max(x0 + 1, 0), WWID - 1);
        samp = c00[p] * xc[yc0 * WWID + xc0] + c01[p] * xc[yc0 * WWID + xc1]
             + c10[p] * xc[yc1 * WWID + xc0] + c11[p] * xc[yc1 * WWID + xc1];
      }
      const float s = samp - xcv;
      const float* wdp = w_deform + (size_t)(c * DDIM) * KK + p;  // SGPR base
      yd0 += wdp[0 * KK] * s;
      yd1 += wdp[1 * KK] * s;
      yd2 += wdp[2 * KK] * s;
      yd3 += wdp[3 * KK] * s;
    }
    const unsigned lo = (unsigned)f2bf(yd0) | ((unsigned)f2bf(yd1) << 16);
    const unsigned hi = (unsigned)f2bf(yd2) | ((unsigned)f2bf(yd3) << 16);
    const int ebase = (((c >> 1) ^ (pl & 7)) << 3) + (c & 1) * 4;  // XOR swizzle
    *reinterpret_cast<uint2*>(&ylds[pl * CDIM + ebase]) = make_uint2(lo, hi);
  };

  {
    float qA[8], qB[8];
    p1_load(qA, RFL(cg * 8));
#pragma unroll
    for (int c2 = 0; c2 < 8; c2 += 2) {
      p1_write(qA);
      p1_load(qB, RFL(cg * 8 + c2 + 1));
      p1_comp(RFL(cg * 8 + c2));
      p1_write(qB);
      if (c2 < 6) p1_load(qA, RFL(cg * 8 + c2 + 2));
      p1_comp(RFL(cg * 8 + c2 + 1));
    }
  }
  __syncthreads();

  // ==== phase 2: MFMA pointwise; 8 waves -> 4(M) x 2(N) grid of 32x32 tiles ====
  const int l15 = tid & 15;
  const int kg  = (tid & 63) >> 4;
  const int Mb = (cg >> 1) * 32;
  const int Nb = (cg & 1) * 32;

  f32x4 acc[2][2];
#pragma unroll
  for (int mi = 0; mi < 2; ++mi)
#pragma unroll
    for (int ni = 0; ni < 2; ++ni)
      acc[mi][ni] = (f32x4){0.f, 0.f, 0.f, 0.f};

#pragma unroll
  for (int ks = 0; ks < 8; ++ks) {          // K = 256 in steps of 32
    bf16x8 bfr[2];
#pragma unroll
    for (int ni = 0; ni < 2; ++ni) {
      const int prow = Nb + ni * 16 + l15;
      const int chunk = ks * 4 + kg;
      const int eb = ((chunk ^ (prow & 7)) << 3);
      bfr[ni] = *reinterpret_cast<const bf16x8*>(&ylds[prow * CDIM + eb]);
    }
    bf16x8 afr[2];
#pragma unroll
    for (int mi = 0; mi < 2; ++mi) {
      const int o = Mb + mi * 16 + l15;
      afr[mi] = *reinterpret_cast<const bf16x8*>(wbf + (size_t)o * CDIM + ks * 32 + kg * 8);
    }
#pragma unroll
    for (int mi = 0; mi < 2; ++mi)
#pragma unroll
      for (int ni = 0; ni < 2; ++ni)
        acc[mi][ni] = __builtin_amdgcn_mfma_f32_16x16x32_bf16(afr[mi], bfr[ni], acc[mi][ni], 0, 0, 0);
  }

  // ==== epilogue: C/D layout col=lane&15, row=(lane>>4)*4+reg ====
  float* on = out + (size_t)n * COUT * HW;
#pragma unroll
  for (int mi = 0; mi < 2; ++mi) {
#pragma unroll
    for (int ni = 0; ni < 2; ++ni) {
      const int pcol = h * WWID + w0 + Nb + ni * 16 + l15;
#pragma unroll
      for (int reg = 0; reg < 4; ++reg) {
        const int o = Mb + mi * 16 + kg * 4 + reg;
        on[(size_t)o * HW + pcol] = acc[mi][ni][reg];
      }
    }
  }
}

// ---------------------------------------------------------------------------
extern "C" void kernel_launch(void* const* d_in, const int* in_sizes, int n_in,
                              void* d_out, int out_size, void* d_ws, size_t ws_size,
                              hipStream_t stream) {
  const float* x        = (const float*)d_in[0];
  const float* w_off    = (const float*)d_in[1];
  const float* b_off    = (const float*)d_in[2];
  const float* w_deform = (const float*)d_in[3];
  const float* w_pw     = (const float*)d_in[4];
  float* out = (float*)d_out;
  unsigned short* wbf = (unsigned short*)d_ws;   // 65536 B

  convert_wpw<<<dim3(COUT * CDIM / 256), dim3(256), 0, stream>>>(w_pw, wbf);
  fused_all<<<dim3(WWID / 64, HH, NN), dim3(512), 0, stream>>>(x, w_off, b_off, w_deform, wbf, out);
}

// Round 7
// 210.910 us; speedup vs baseline: 1.5460x; 1.5460x over previous
//
#include <hip/hip_runtime.h>

#define DDIM   4        // D = 2*K-2
#define CIN    64
#define COUT   128
#define CDIM   256      // CIN*DDIM
#define HH     128
#define WWID   128
#define NN     4
#define KK     9        // K*K
#define OFFC   18       // 2*K*K
#define HW     (HH * WWID)

// ---- LDS layout (floats) ----
// xs: 8 wave-private slices of 511 floats (phase0 3x66=198 @stride 66; phase1 7x72 @stride 73)
#define XS_SLICE  511
#define XS_TOTAL  (8 * XS_SLICE)            // 4088
#define TL_OFF    XS_TOTAL                  // tl[18][64] = 1152 floats
#define YL_OFF    (TL_OFF + OFFC * 64)      // 5240
#define SMEM_FLOATS (YL_OFF + 8192)         // ylds 64x256 bf16 = 32768 B -> total 53728 B
// part bf16[8][18][64] (18432 B) aliases the ylds region, separated by barriers.

typedef __attribute__((ext_vector_type(8))) short bf16x8;
typedef __attribute__((ext_vector_type(4))) float f32x4;

#define RFL(x) __builtin_amdgcn_readfirstlane(x)

__device__ __forceinline__ unsigned short f2bf(float f) {
  union { float f; unsigned u; } c; c.f = f;
  unsigned u = c.u;
  return (unsigned short)((u + 0x7FFFu + ((u >> 16) & 1u)) >> 16);  // RNE
}
__device__ __forceinline__ float bf2f(unsigned short u) {
  union { unsigned u; float f; } c; c.u = (unsigned)u << 16;
  return c.f;
}

__global__ void convert_wpw(const float* __restrict__ w_pw, unsigned short* __restrict__ wbf) {
  int i = blockIdx.x * 256 + threadIdx.x;
  if (i < COUT * CDIM) wbf[i] = f2bf(w_pw[i]);
}

// ---------------------------------------------------------------------------
// Mega-fused kernel: offset-conv + bilinear deform + depthwise + MFMA pointwise.
// 512 thr = 8 waves; strip = 64 pixels (one h row). Phase-1 T14 register
// prefetch; chunked XCD swizzle. launch_bounds(512,2): LDS caps us at
// 2 blocks/CU anyway, so let the allocator use up to 256 VGPRs (NO spills —
// round 6's 64-VGPR spill storm cost 3x).
// ---------------------------------------------------------------------------
__global__ __launch_bounds__(512, 2)
void fused_all(const float* __restrict__ x, const float* __restrict__ w_off,
               const float* __restrict__ b_off, const float* __restrict__ w_deform,
               const unsigned short* __restrict__ wbf, float* __restrict__ out) {
  __shared__ float smem[SMEM_FLOATS];

  // chunked XCD swizzle (bijective: 1024 blocks = 8 XCDs x 128)
  const int lin = blockIdx.x + 2 * blockIdx.y + 256 * blockIdx.z;
  const int swz = ((lin & 7) << 7) + (lin >> 3);
  const int n  = swz >> 8;
  const int h  = (swz >> 1) & 127;
  const int w0 = (swz & 1) * 64;

  const int tid = threadIdx.x;
  const int pl = tid & 63;          // pixel within strip (== lane)
  const int cg = tid >> 6;          // wave id
  const int w = w0 + pl;

  const float* xn = x + (size_t)n * CIN * HW;
  float* xsl = smem + cg * XS_SLICE;                       // wave-private slice
  float* tl  = smem + TL_OFF;                              // [18][64]
  unsigned short* pt   = (unsigned short*)(smem + YL_OFF); // partials (bf16) alias
  unsigned short* ylds = (unsigned short*)(smem + YL_OFF); // [64][256] bf16

  // ==== phase 0: offset-conv partials (this wave's 8 channels), simple ====
  float ao[OFFC];
#pragma unroll
  for (int o = 0; o < OFFC; ++o) ao[o] = 0.f;

#pragma unroll 1
  for (int ci = 0; ci < 8; ++ci) {
    const int c = RFL(cg * 8 + ci);
    const float* xc = xn + (size_t)c * HW;
    // stage 3x66 (rows h-1..h+1, cols w0-1..w0+64), zero-filled borders
    for (int i = pl; i < 198; i += 64) {
      const int tr = i / 66, tc = i - tr * 66;
      const int gy = h - 1 + tr, gx = w0 - 1 + tc;
      float v = 0.f;
      if (gy >= 0 && gy < HH && gx >= 0 && gx < WWID) v = xc[gy * WWID + gx];
      xsl[tr * 66 + tc] = v;    // wave-private: per-wave LDS ordering suffices
    }
    const float center = xsl[66 + pl + 1];
    float v[KK];
#pragma unroll
    for (int p = 0; p < KK; ++p)
      v[p] = xsl[(p / 3) * 66 + pl + (p % 3)] - center;   // v[4]==0
#pragma unroll
    for (int o = 0; o < OFFC; ++o) {
      const float* wrow = w_off + ((size_t)o * CIN + c) * KK;  // SGPR base
      float a = ao[o];
#pragma unroll
      for (int p = 0; p < KK; ++p) {
        if (p == 4) continue;
        a += wrow[p] * v[p];
      }
      ao[o] = a;
    }
  }
#pragma unroll
  for (int o = 0; o < OFFC; ++o) pt[(cg * OFFC + o) * 64 + pl] = f2bf(ao[o]);
  __syncthreads();

  // ==== cross-wave reduce -> tl[18][64] ====
  for (int idx = tid; idx < OFFC * 64; idx += 512) {
    const int o = idx >> 6, px = idx & 63;
    float s = b_off[o];
#pragma unroll
    for (int w8 = 0; w8 < 8; ++w8) s += bf2f(pt[(w8 * OFFC + o) * 64 + px]);
    tl[o * 64 + px] = s;
  }
  __syncthreads();    // fences pt reads before ylds (alias) writes

  // ==== tap precompute (per pixel pl); 7-row x 72-col window ====
  const int row0 = min(max(h - 3, 0), HH - 7);
  const int col0 = min(max(w0 - 3, 0), WWID - 72);
  const int hc  = h - row0;
  const int wcb = w0 - col0;
  unsigned pk[KK];
  float c00[KK], c01[KK], c10[KK], c11[KK];
  unsigned inmask = 0;
#pragma unroll
  for (int p = 0; p < KK; ++p) {
    const float dy = tl[(2 * p) * 64 + pl];
    const float dx = tl[(2 * p + 1) * 64 + pl];
    const float py  = dy + (float)(h + p / 3 - 1);
    const float pxx = dx + (float)(w + p % 3 - 1);
    const float fy = floorf(py), fx = floorf(pxx);
    const int y0 = (int)fy, x0 = (int)fx;
    const int y1 = y0 + 1,  x1 = x0 + 1;
    const float ay = py - fy, ax = pxx - fx;
    const bool vy0 = (y0 >= 0) && (y0 < HH), vy1 = (y1 >= 0) && (y1 < HH);
    const bool vx0 = (x0 >= 0) && (x0 < WWID), vx1 = (x1 >= 0) && (x1 < WWID);
    const int yc0 = min(max(y0, 0), HH - 1),  yc1 = min(max(y1, 0), HH - 1);
    const int xc0 = min(max(x0, 0), WWID - 1), xc1 = min(max(x1, 0), WWID - 1);
    const int ty0 = yc0 - row0, ty1 = yc1 - row0;
    const int tx0 = xc0 - col0, tx1 = xc1 - col0;
    if ((unsigned)ty0 < 7u && (unsigned)ty1 < 7u && (unsigned)tx0 < 72u && (unsigned)tx1 < 72u)
      inmask |= 1u << p;
    pk[p] = (unsigned)(ty0 & 255) | ((unsigned)(ty1 & 255) << 8)
          | ((unsigned)(tx0 & 255) << 16) | ((unsigned)(tx1 & 255) << 24);
    c00[p] = (vy0 && vx0) ? (1.f - ay) * (1.f - ax) : 0.f;
    c01[p] = (vy0 && vx1) ? (1.f - ay) * ax         : 0.f;
    c10[p] = (vy1 && vx0) ? ay * (1.f - ax)         : 0.f;
    c11[p] = (vy1 && vx1) ? ay * ax                 : 0.f;
  }

  // ==== phase 1: prefetched halo staging + LDS bilinear + depthwise -> ylds ====
  int g1[8], l1[8];
#pragma unroll
  for (int k = 0; k < 8; ++k) {
    const int i = pl + k * 64;
    const int r = i / 72, cl = i - r * 72;
    g1[k] = (row0 + r) * WWID + col0 + cl;
    l1[k] = r * 73 + cl;
  }
  auto p1_load = [&](float* b, int c) {
    const float* xc = xn + (size_t)c * HW;
#pragma unroll
    for (int k = 0; k < 8; ++k) {
      if (k < 7) b[k] = xc[g1[k]];
      else if (pl < 56) b[7] = xc[g1[7]];
    }
  };
  auto p1_write = [&](const float* b) {
#pragma unroll
    for (int k = 0; k < 8; ++k) {
      if (k < 7) xsl[l1[k]] = b[k];
      else if (pl < 56) xsl[l1[7]] = b[7];
    }
  };
  auto p1_comp = [&](int c) {
    const float* xc = xn + (size_t)c * HW;   // cold path only
    const float xcv = xsl[hc * 73 + wcb + pl];
    float yd0 = 0.f, yd1 = 0.f, yd2 = 0.f, yd3 = 0.f;
#pragma unroll
    for (int p = 0; p < KK; ++p) {
      float samp;
      if (inmask & (1u << p)) {             // hot: in-window LDS gather
        const unsigned k4 = pk[p];
        const int ty0 = k4 & 255, ty1 = (k4 >> 8) & 255;
        const int tx0 = (k4 >> 16) & 255, tx1 = k4 >> 24;
        samp = c00[p] * xsl[ty0 * 73 + tx0] + c01[p] * xsl[ty0 * 73 + tx1]
             + c10[p] * xsl[ty1 * 73 + tx0] + c11[p] * xsl[ty1 * 73 + tx1];
      } else {                              // cold: recompute + global gather
        const float dy = tl[(2 * p) * 64 + pl];
        const float dx = tl[(2 * p + 1) * 64 + pl];
        const float py  = dy + (float)(h + p / 3 - 1);
        const float pxx = dx + (float)(w + p % 3 - 1);
        const float fy = floorf(py), fx = floorf(pxx);
        const int y0 = (int)fy, x0 = (int)fx;
        const int yc0 = min(max(y0, 0), HH - 1),  yc1 = min(max(y0 + 1, 0), HH - 1);
        const int xc0 = min(max(x0, 0), WWID - 1), xc1 = min(max(x0 + 1, 0), WWID - 1);
        samp = c00[p] * xc[yc0 * WWID + xc0] + c01[p] * xc[yc0 * WWID + xc1]
             + c10[p] * xc[yc1 * WWID + xc0] + c11[p] * xc[yc1 * WWID + xc1];
      }
      const float s = samp - xcv;
      const float* wdp = w_deform + (size_t)(c * DDIM) * KK + p;  // SGPR base
      yd0 += wdp[0 * KK] * s;
      yd1 += wdp[1 * KK] * s;
      yd2 += wdp[2 * KK] * s;
      yd3 += wdp[3 * KK] * s;
    }
    const unsigned lo = (unsigned)f2bf(yd0) | ((unsigned)f2bf(yd1) << 16);
    const unsigned hi = (unsigned)f2bf(yd2) | ((unsigned)f2bf(yd3) << 16);
    const int ebase = (((c >> 1) ^ (pl & 7)) << 3) + (c & 1) * 4;  // XOR swizzle
    *reinterpret_cast<uint2*>(&ylds[pl * CDIM + ebase]) = make_uint2(lo, hi);
  };

  {
    float qA[8], qB[8];
    p1_load(qA, RFL(cg * 8));
#pragma unroll
    for (int c2 = 0; c2 < 8; c2 += 2) {
      p1_write(qA);
      p1_load(qB, RFL(cg * 8 + c2 + 1));
      p1_comp(RFL(cg * 8 + c2));
      p1_write(qB);
      if (c2 < 6) p1_load(qA, RFL(cg * 8 + c2 + 2));
      p1_comp(RFL(cg * 8 + c2 + 1));
    }
  }
  __syncthreads();

  // ==== phase 2: MFMA pointwise; 8 waves -> 4(M) x 2(N) grid of 32x32 tiles ====
  const int l15 = tid & 15;
  const int kg  = (tid & 63) >> 4;
  const int Mb = (cg >> 1) * 32;
  const int Nb = (cg & 1) * 32;

  f32x4 acc[2][2];
#pragma unroll
  for (int mi = 0; mi < 2; ++mi)
#pragma unroll
    for (int ni = 0; ni < 2; ++ni)
      acc[mi][ni] = (f32x4){0.f, 0.f, 0.f, 0.f};

#pragma unroll
  for (int ks = 0; ks < 8; ++ks) {          // K = 256 in steps of 32
    bf16x8 bfr[2];
#pragma unroll
    for (int ni = 0; ni < 2; ++ni) {
      const int prow = Nb + ni * 16 + l15;
      const int chunk = ks * 4 + kg;
      const int eb = ((chunk ^ (prow & 7)) << 3);
      bfr[ni] = *reinterpret_cast<const bf16x8*>(&ylds[prow * CDIM + eb]);
    }
    bf16x8 afr[2];
#pragma unroll
    for (int mi = 0; mi < 2; ++mi) {
      const int o = Mb + mi * 16 + l15;
      afr[mi] = *reinterpret_cast<const bf16x8*>(wbf + (size_t)o * CDIM + ks * 32 + kg * 8);
    }
#pragma unroll
    for (int mi = 0; mi < 2; ++mi)
#pragma unroll
      for (int ni = 0; ni < 2; ++ni)
        acc[mi][ni] = __builtin_amdgcn_mfma_f32_16x16x32_bf16(afr[mi], bfr[ni], acc[mi][ni], 0, 0, 0);
  }

  // ==== epilogue: C/D layout col=lane&15, row=(lane>>4)*4+reg ====
  float* on = out + (size_t)n * COUT * HW;
#pragma unroll
  for (int mi = 0; mi < 2; ++mi) {
#pragma unroll
    for (int ni = 0; ni < 2; ++ni) {
      const int pcol = h * WWID + w0 + Nb + ni * 16 + l15;
#pragma unroll
      for (int reg = 0; reg < 4; ++reg) {
        const int o = Mb + mi * 16 + kg * 4 + reg;
        on[(size_t)o * HW + pcol] = acc[mi][ni][reg];
      }
    }
  }
}

// ---------------------------------------------------------------------------
extern "C" void kernel_launch(void* const* d_in, const int* in_sizes, int n_in,
                              void* d_out, int out_size, void* d_ws, size_t ws_size,
                              hipStream_t stream) {
  const float* x        = (const float*)d_in[0];
  const float* w_off    = (const float*)d_in[1];
  const float* b_off    = (const float*)d_in[2];
  const float* w_deform = (const float*)d_in[3];
  const float* w_pw     = (const float*)d_in[4];
  float* out = (float*)d_out;
  unsigned short* wbf = (unsigned short*)d_ws;   // 65536 B

  convert_wpw<<<dim3(COUT * CDIM / 256), dim3(256), 0, stream>>>(w_pw, wbf);
  fused_all<<<dim3(WWID / 64, HH, NN), dim3(512), 0, stream>>>(x, w_off, b_off, w_deform, wbf, out);
}

// Round 8
// 152.058 us; speedup vs baseline: 2.1443x; 1.3870x over previous
//
#include <hip/hip_runtime.h>

#define DDIM   4        // D = 2*K-2
#define CIN    64
#define COUT   128
#define CDIM   256      // CIN*DDIM
#define HH     128
#define WWID   128
#define NN     4
#define KK     9        // K*K
#define OFFC   18       // 2*K*K
#define HW     (HH * WWID)

// ---- LDS layout (floats) ----
// xs: 8 wave-private slices; phase0 3x66=198 @stride 66; phase1 6 rows x 72 cols @ stride 73
#define XS_SLICE  438                       // 6*73
#define XS_TOTAL  (8 * XS_SLICE)            // 3504
#define TL_OFF    XS_TOTAL                  // tl[18][64] = 1152 floats
#define YL_OFF    (TL_OFF + OFFC * 64)      // 4656
#define SMEM_FLOATS (YL_OFF + 8192)         // ylds 64x256 bf16 = 32768 B -> total 51392 B
// part bf16[8][18][64] (18432 B) aliases the ylds region, separated by barriers.

typedef __attribute__((ext_vector_type(8))) short bf16x8;
typedef __attribute__((ext_vector_type(4))) float f32x4;

#define RFL(x) __builtin_amdgcn_readfirstlane(x)

__device__ __forceinline__ unsigned short f2bf(float f) {
  union { float f; unsigned u; } c; c.f = f;
  unsigned u = c.u;
  return (unsigned short)((u + 0x7FFFu + ((u >> 16) & 1u)) >> 16);  // RNE
}
__device__ __forceinline__ float bf2f(unsigned short u) {
  union { unsigned u; float f; } c; c.u = (unsigned)u << 16;
  return c.f;
}

__global__ void convert_wpw(const float* __restrict__ w_pw, unsigned short* __restrict__ wbf) {
  int i = blockIdx.x * 256 + threadIdx.x;
  if (i < COUT * CDIM) wbf[i] = f2bf(w_pw[i]);
}

// ---------------------------------------------------------------------------
// Mega-fused kernel. 512 thr = 8 waves; strip = 64 pixels (one h row).
// Phase 1 uses a ZERO-PADDED unclamped 6x72 window (stride 73) so zero-pad
// semantics come from staged zeros; hot waves (__all taps in-window) run a
// BRANCH-FREE batched 36-gather path (ds_read2-pairable, all loads hoistable).
// Cold waves (rare: |offset|>~1 at image border) use the exact per-tap path.
// ---------------------------------------------------------------------------
__global__ __launch_bounds__(512, 2)
void fused_all(const float* __restrict__ x, const float* __restrict__ w_off,
               const float* __restrict__ b_off, const float* __restrict__ w_deform,
               const unsigned short* __restrict__ wbf, float* __restrict__ out) {
  __shared__ float smem[SMEM_FLOATS];

  // chunked XCD swizzle (bijective: 1024 blocks = 8 XCDs x 128)
  const int lin = blockIdx.x + 2 * blockIdx.y + 256 * blockIdx.z;
  const int swz = ((lin & 7) << 7) + (lin >> 3);
  const int n  = swz >> 8;
  const int h  = (swz >> 1) & 127;
  const int w0 = (swz & 1) * 64;

  const int tid = threadIdx.x;
  const int pl = tid & 63;          // pixel within strip (== lane)
  const int cg = tid >> 6;          // wave id
  const int w = w0 + pl;
  const int pix = h * WWID + w;

  const float* xn = x + (size_t)n * CIN * HW;
  float* xsl = smem + cg * XS_SLICE;                       // wave-private slice
  float* tl  = smem + TL_OFF;                              // [18][64]
  unsigned short* pt   = (unsigned short*)(smem + YL_OFF); // partials (bf16) alias
  unsigned short* ylds = (unsigned short*)(smem + YL_OFF); // [64][256] bf16

  // ==== phase 0: offset-conv partials (this wave's 8 channels) ====
  float ao[OFFC];
#pragma unroll
  for (int o = 0; o < OFFC; ++o) ao[o] = 0.f;

#pragma unroll 1
  for (int ci = 0; ci < 8; ++ci) {
    const int c = RFL(cg * 8 + ci);
    const float* xc = xn + (size_t)c * HW;
    for (int i = pl; i < 198; i += 64) {
      const int tr = i / 66, tc = i - tr * 66;
      const int gy = h - 1 + tr, gx = w0 - 1 + tc;
      float v = 0.f;
      if (gy >= 0 && gy < HH && gx >= 0 && gx < WWID) v = xc[gy * WWID + gx];
      xsl[tr * 66 + tc] = v;    // wave-private: per-wave LDS ordering suffices
    }
    const float center = xsl[66 + pl + 1];
    float v[KK];
#pragma unroll
    for (int p = 0; p < KK; ++p)
      v[p] = xsl[(p / 3) * 66 + pl + (p % 3)] - center;   // v[4]==0
#pragma unroll
    for (int o = 0; o < OFFC; ++o) {
      const float* wrow = w_off + ((size_t)o * CIN + c) * KK;  // SGPR base
      float a = ao[o];
#pragma unroll
      for (int p = 0; p < KK; ++p) {
        if (p == 4) continue;
        a += wrow[p] * v[p];
      }
      ao[o] = a;
    }
  }
#pragma unroll
  for (int o = 0; o < OFFC; ++o) pt[(cg * OFFC + o) * 64 + pl] = f2bf(ao[o]);
  __syncthreads();

  // ==== cross-wave reduce -> tl[18][64] ====
  for (int idx = tid; idx < OFFC * 64; idx += 512) {
    const int o = idx >> 6, px = idx & 63;
    float s = b_off[o];
#pragma unroll
    for (int w8 = 0; w8 < 8; ++w8) s += bf2f(pt[(w8 * OFFC + o) * 64 + px]);
    tl[o * 64 + px] = s;
  }
  __syncthreads();    // fences pt reads before ylds (alias) writes

  // ==== tap precompute; UNCLAMPED window origin (row0,col0) may be <0 ====
  const int row0 = h - 3;
  const int col0 = w0 - 3;
  float c00[KK], c01[KK], c10[KK], c11[KK];   // UNMASKED bilinear products
  int gbase[KK];
  unsigned hotm = 0;
#pragma unroll
  for (int p = 0; p < KK; ++p) {
    const float dy = tl[(2 * p) * 64 + pl];
    const float dx = tl[(2 * p + 1) * 64 + pl];
    const float py  = dy + (float)(h + p / 3 - 1);
    const float pxx = dx + (float)(w + p % 3 - 1);
    const float fy = floorf(py), fx = floorf(pxx);
    const int y0 = (int)fy, x0 = (int)fx;
    const float ay = py - fy, ax = pxx - fx;
    const int ty0 = y0 - row0;            // window row of top corner
    const int tx0 = x0 - col0;            // window col of left corner
    if ((unsigned)ty0 <= 4u && (unsigned)tx0 <= 70u) hotm |= 1u << p;
    gbase[p] = ty0 * 73 + tx0;
    const float by = 1.f - ay, bx = 1.f - ax;
    c00[p] = by * bx;  c01[p] = by * ax;
    c10[p] = ay * bx;  c11[p] = ay * ax;
  }
  const bool hot = (__all((int)(hotm == 0x1FFu)) != 0);

  // ==== staging geometry: 6x72 window (432 elems), zero-fill outside image ====
  int g1[7], l1[7];
  unsigned ok7 = 0;                       // in-image mask
#pragma unroll
  for (int k = 0; k < 7; ++k) {
    const int i = pl + k * 64;
    const int r = i / 72, cl = i - r * 72;
    const int gy = row0 + r, gx = col0 + cl;
    const bool act = (i < 432) && gy >= 0 && gy < HH && gx >= 0 && gx < WWID;
    g1[k] = act ? (gy * WWID + gx) : 0;
    l1[k] = r * 73 + cl;
    if (act) ok7 |= 1u << k;
  }
  auto p1_load = [&](float* b, int c) {
    const float* xc = xn + (size_t)c * HW;
#pragma unroll
    for (int k = 0; k < 7; ++k)
      b[k] = ((ok7 >> k) & 1) ? xc[g1[k]] : 0.f;
  };
  auto p1_write = [&](const float* b) {
#pragma unroll
    for (int k = 0; k < 7; ++k) {
      if (k < 6) xsl[l1[k]] = b[k];
      else if (pl < 48) xsl[l1[6]] = b[6];   // 432 - 384 = 48 tail lanes
    }
  };
  auto store_y = [&](int c, float yd0, float yd1, float yd2, float yd3) {
    const unsigned lo = (unsigned)f2bf(yd0) | ((unsigned)f2bf(yd1) << 16);
    const unsigned hi = (unsigned)f2bf(yd2) | ((unsigned)f2bf(yd3) << 16);
    const int ebase = (((c >> 1) ^ (pl & 7)) << 3) + (c & 1) * 4;  // XOR swizzle
    *reinterpret_cast<uint2*>(&ylds[pl * CDIM + ebase]) = make_uint2(lo, hi);
  };

  // hot: branch-free, fully batched gathers (compiler can hoist all 36+1 reads)
  auto p1_comp_hot = [&](int c) {
    const float xcv = xsl[3 * 73 + pl + 3];      // window cell (h, w)
    float g00[KK], g01[KK], g10[KK], g11[KK];
#pragma unroll
    for (int p = 0; p < KK; ++p) {
      const float* bp = &xsl[gbase[p]];
      g00[p] = bp[0];  g01[p] = bp[1];
      g10[p] = bp[73]; g11[p] = bp[74];
    }
    float yd0 = 0.f, yd1 = 0.f, yd2 = 0.f, yd3 = 0.f;
#pragma unroll
    for (int p = 0; p < KK; ++p) {
      const float samp = c00[p] * g00[p] + c01[p] * g01[p]
                       + c10[p] * g10[p] + c11[p] * g11[p];
      const float s = samp - xcv;
      const float* wdp = w_deform + (size_t)(c * DDIM) * KK + p;  // SGPR base
      yd0 += wdp[0 * KK] * s;
      yd1 += wdp[1 * KK] * s;
      yd2 += wdp[2 * KK] * s;
      yd3 += wdp[3 * KK] * s;
    }
    store_y(c, yd0, yd1, yd2, yd3);
  };

  // cold: exact per-tap path (clipped global gathers, masked coefs)
  auto p1_comp_cold = [&](int c) {
    const float* xc = xn + (size_t)c * HW;
    const float xcv = xc[pix];
    float yd0 = 0.f, yd1 = 0.f, yd2 = 0.f, yd3 = 0.f;
#pragma unroll
    for (int p = 0; p < KK; ++p) {
      float samp;
      if (hotm & (1u << p)) {
        const float* bp = &xsl[gbase[p]];
        samp = c00[p] * bp[0] + c01[p] * bp[1] + c10[p] * bp[73] + c11[p] * bp[74];
      } else {
        const float dy = tl[(2 * p) * 64 + pl];
        const float dx = tl[(2 * p + 1) * 64 + pl];
        const float py  = dy + (float)(h + p / 3 - 1);
        const float pxx = dx + (float)(w + p % 3 - 1);
        const float fy = floorf(py), fx = floorf(pxx);
        const int y0 = (int)fy, x0 = (int)fx;
        const int y1 = y0 + 1,  x1 = x0 + 1;
        const bool vy0 = (y0 >= 0) && (y0 < HH), vy1 = (y1 >= 0) && (y1 < HH);
        const bool vx0 = (x0 >= 0) && (x0 < WWID), vx1 = (x1 >= 0) && (x1 < WWID);
        const int yc0 = min(max(y0, 0), HH - 1),  yc1 = min(max(y1, 0), HH - 1);
        const int xc0 = min(max(x0, 0), WWID - 1), xc1 = min(max(x1, 0), WWID - 1);
        const float m00 = (vy0 && vx0) ? c00[p] : 0.f;
        const float m01 = (vy0 && vx1) ? c01[p] : 0.f;
        const float m10 = (vy1 && vx0) ? c10[p] : 0.f;
        const float m11 = (vy1 && vx1) ? c11[p] : 0.f;
        samp = m00 * xc[yc0 * WWID + xc0] + m01 * xc[yc0 * WWID + xc1]
             + m10 * xc[yc1 * WWID + xc0] + m11 * xc[yc1 * WWID + xc1];
      }
      const float s = samp - xcv;
      const float* wdp = w_deform + (size_t)(c * DDIM) * KK + p;
      yd0 += wdp[0 * KK] * s;
      yd1 += wdp[1 * KK] * s;
      yd2 += wdp[2 * KK] * s;
      yd3 += wdp[3 * KK] * s;
    }
    store_y(c, yd0, yd1, yd2, yd3);
  };

  // ping-pong pipeline: global->reg prefetch of next channel's window
  auto pipeline = [&](auto comp) {
    float qA[7], qB[7];
    p1_load(qA, RFL(cg * 8));
#pragma unroll
    for (int c2 = 0; c2 < 8; c2 += 2) {
      p1_write(qA);
      p1_load(qB, RFL(cg * 8 + c2 + 1));
      comp(RFL(cg * 8 + c2));
      p1_write(qB);
      if (c2 < 6) p1_load(qA, RFL(cg * 8 + c2 + 2));
      comp(RFL(cg * 8 + c2 + 1));
    }
  };
  if (hot) pipeline(p1_comp_hot);
  else     pipeline(p1_comp_cold);
  __syncthreads();

  // ==== phase 2: MFMA pointwise; 8 waves -> 4(M) x 2(N) grid of 32x32 tiles ====
  const int l15 = tid & 15;
  const int kg  = (tid & 63) >> 4;
  const int Mb = (cg >> 1) * 32;
  const int Nb = (cg & 1) * 32;

  f32x4 acc[2][2];
#pragma unroll
  for (int mi = 0; mi < 2; ++mi)
#pragma unroll
    for (int ni = 0; ni < 2; ++ni)
      acc[mi][ni] = (f32x4){0.f, 0.f, 0.f, 0.f};

#pragma unroll
  for (int ks = 0; ks < 8; ++ks) {          // K = 256 in steps of 32
    bf16x8 bfr[2];
#pragma unroll
    for (int ni = 0; ni < 2; ++ni) {
      const int prow = Nb + ni * 16 + l15;
      const int chunk = ks * 4 + kg;
      const int eb = ((chunk ^ (prow & 7)) << 3);
      bfr[ni] = *reinterpret_cast<const bf16x8*>(&ylds[prow * CDIM + eb]);
    }
    bf16x8 afr[2];
#pragma unroll
    for (int mi = 0; mi < 2; ++mi) {
      const int o = Mb + mi * 16 + l15;
      afr[mi] = *reinterpret_cast<const bf16x8*>(wbf + (size_t)o * CDIM + ks * 32 + kg * 8);
    }
#pragma unroll
    for (int mi = 0; mi < 2; ++mi)
#pragma unroll
      for (int ni = 0; ni < 2; ++ni)
        acc[mi][ni] = __builtin_amdgcn_mfma_f32_16x16x32_bf16(afr[mi], bfr[ni], acc[mi][ni], 0, 0, 0);
  }

  // ==== epilogue: C/D layout col=lane&15, row=(lane>>4)*4+reg ====
  float* on = out + (size_t)n * COUT * HW;
#pragma unroll
  for (int mi = 0; mi < 2; ++mi) {
#pragma unroll
    for (int ni = 0; ni < 2; ++ni) {
      const int pcol = h * WWID + w0 + Nb + ni * 16 + l15;
#pragma unroll
      for (int reg = 0; reg < 4; ++reg) {
        const int o = Mb + mi * 16 + kg * 4 + reg;
        on[(size_t)o * HW + pcol] = acc[mi][ni][reg];
      }
    }
  }
}

// ---------------------------------------------------------------------------
extern "C" void kernel_launch(void* const* d_in, const int* in_sizes, int n_in,
                              void* d_out, int out_size, void* d_ws, size_t ws_size,
                              hipStream_t stream) {
  const float* x        = (const float*)d_in[0];
  const float* w_off    = (const float*)d_in[1];
  const float* b_off    = (const float*)d_in[2];
  const float* w_deform = (const float*)d_in[3];
  const float* w_pw     = (const float*)d_in[4];
  float* out = (float*)d_out;
  unsigned short* wbf = (unsigned short*)d_ws;   // 65536 B

  convert_wpw<<<dim3(COUT * CDIM / 256), dim3(256), 0, stream>>>(w_pw, wbf);
  fused_all<<<dim3(WWID / 64, HH, NN), dim3(512), 0, stream>>>(x, w_off, b_off, w_deform, wbf, out);
}